// Round 4
// baseline (361.694 us; speedup 1.0000x reference)
//
#include <hip/hip_runtime.h>
#include <hip/hip_bf16.h>
#include <cstdint>

// LSTMCell B=8192, IN=H=1024, fp32 in/out.
// R4 changes vs R3 (plateau-bound at the 2-barrier global_load_lds structure):
//  - B matrix NEVER touches LDS: Bt2 is pre-packed in exact MFMA-B-fragment
//    order [jg][kt][gate][lane]x16B, so each fragment is one coalesced
//    global_load_dwordx4 (L2-resident). B loads are register loads -> not
//    drained at barriers, compiler pipelines with fine-grained vmcnt.
//  - A: global_load_lds into a DOUBLE-buffered LDS (2x16KB), ONE barrier per
//    k-iter; prefetch for iter k+1 issued right after the barrier, drained at
//    the next barrier (hidden under 32 MFMAs of compute).
//  - A-read XOR swizzle kept (R2 pattern, measured 0 conflicts).

#define B_DIM 8192
#define H_DIM 1024
#define K2    2048   // IN + H
#define N4    4096   // 4 * H
#define BK    64
#define BM    128
#define BN    256    // = 2 j-groups of 32 j x 4 gates

typedef __bf16 bf16x8 __attribute__((ext_vector_type(8)));
typedef float  f32x16 __attribute__((ext_vector_type(16)));

__device__ __forceinline__ void async_load16(const __bf16* g, __bf16* l) {
  __builtin_amdgcn_global_load_lds(
      (__attribute__((address_space(1))) void*)(g),
      (__attribute__((address_space(3))) void*)(l),
      16, 0, 0);
}

__device__ __forceinline__ float sigm(float x) {
  return 1.0f / (1.0f + __expf(-x));
}
__device__ __forceinline__ float tanh_fast(float x) {
  return 2.0f / (1.0f + __expf(-2.0f * x)) - 1.0f;
}

// ---------------- cast A = [x | h] -> bf16 [8192][2048] ----------------
__global__ void cast_a(const float* __restrict__ x, const float* __restrict__ h,
                       __bf16* __restrict__ A) {
  int row = blockIdx.x;
  int k = threadIdx.x << 3;
  const float* src = (k < H_DIM) ? (x + (size_t)row * H_DIM + k)
                                 : (h + (size_t)row * H_DIM + (k - H_DIM));
  float4 v0 = *(const float4*)src;
  float4 v1 = *(const float4*)(src + 4);
  bf16x8 o;
  o[0] = (__bf16)v0.x; o[1] = (__bf16)v0.y; o[2] = (__bf16)v0.z; o[3] = (__bf16)v0.w;
  o[4] = (__bf16)v1.x; o[5] = (__bf16)v1.y; o[6] = (__bf16)v1.z; o[7] = (__bf16)v1.w;
  *(bf16x8*)&A[(size_t)row * K2 + k] = o;
}

// ------- pack weights into MFMA-B-fragment order Bt2[jg][kt][gate][lane]x8elem -------
// jg = j>>5 (0..31), kt = k>>4 (0..127), lane = (k>>3 & 1)*32 + (j&31),
// elem e = k&7. Value = W_gate[k][j] (k<1024: input weights, else hidden).
// grid: (K2/64, H/32, 4 gates), block 256.
__global__ void cast_w(const float* __restrict__ Wii, const float* __restrict__ Wif,
                       const float* __restrict__ Wig, const float* __restrict__ Wio,
                       const float* __restrict__ Whi, const float* __restrict__ Whf,
                       const float* __restrict__ Whg, const float* __restrict__ Who,
                       __bf16* __restrict__ Bt2) {
  __shared__ float tile[64][33];
  int k0 = blockIdx.x * 64;
  int jg = blockIdx.y;          // j-group
  int j0 = jg * 32;
  int gate = blockIdx.z;
  const float* Wi[4] = {Wii, Wif, Wig, Wio};
  const float* Wh[4] = {Whi, Whf, Whg, Who};
  const float* W = (k0 < H_DIM) ? Wi[gate] : Wh[gate];
  int kb = (k0 < H_DIM) ? k0 : (k0 - H_DIM);

  int col = threadIdx.x & 31;
  int rr  = threadIdx.x >> 5;  // 0..7
#pragma unroll
  for (int p = 0; p < 8; ++p)
    tile[p * 8 + rr][col] = W[(size_t)(kb + p * 8 + rr) * H_DIM + j0 + col];
  __syncthreads();

  int jj = threadIdx.x & 31;
  int kq = threadIdx.x >> 5;          // 0..7 : kt_local = kq>>1, h8 = kq&1
  int kt = (k0 >> 4) + (kq >> 1);
  int h8 = kq & 1;
  bf16x8 o;
#pragma unroll
  for (int e = 0; e < 8; ++e) o[e] = (__bf16)tile[kq * 8 + e][jj];
  size_t chunk = ((size_t)jg * 128 + kt) * 4 + gate;
  *(bf16x8*)&Bt2[chunk * 512 + (h8 * 32 + jj) * 8] = o;
}

// ---------------- fused GEMM + LSTM gate epilogue ----------------
// grid: (8192/128, 4096/256) = (64, 16), block 256 (4 waves)
// wave tile 64x128 (2m x 4gates of 32x32), BK=64, 32x32x16 bf16 MFMA.
__global__ __launch_bounds__(256, 2) void lstm_gemm(
    const __bf16* __restrict__ A,    // [8192][2048]
    const __bf16* __restrict__ Bt2,  // fragment-packed weights
    const float* __restrict__ c,
    const float* __restrict__ bi, const float* __restrict__ bf_,
    const float* __restrict__ bg, const float* __restrict__ bo,
    float* __restrict__ out_c, float* __restrict__ out_h) {
  // A LDS: row stride 64 elems = 128 B; physical 16B slot s of row r holds
  // global segment s ^ (r&7). Double-buffered.
  __shared__ __align__(16) __bf16 As[2][BM * BK];   // 2 x 16 KB

  const int tid  = threadIdx.x;
  const int wave = tid >> 6;
  const int lane = tid & 63;
  const int wm   = wave >> 1;      // 0..1 : M half (64 rows)
  const int wn   = wave & 1;       // 0..1 : j-group within block
  const int m0   = blockIdx.x * BM;
  const int jg   = blockIdx.y * 2 + wn;

  f32x16 acc[2][4] = {};

  const int l31 = lane & 31;
  const int h8  = lane >> 5;

  // A staging: chunk = 8 rows x 64 elems = 1 KiB; wave stages 4 chunks.
  const int rin  = lane >> 3;
  const int slot = lane & 7;
  const int sg   = slot ^ rin;                 // XOR swizzle
  const __bf16* gA[4];
  int lA[4];
#pragma unroll
  for (int cc = 0; cc < 4; ++cc) {
    int r = wave * 32 + cc * 8 + rin;
    gA[cc] = A + (size_t)(m0 + r) * K2 + sg * 8;
    lA[cc] = (wave * 4 + cc) * 512;
  }

  // B: per (kt, gate) fragment at chunk ((jg*128 + kt)*4 + gate)*512 + lane*8
  const __bf16* bbase = Bt2 + ((size_t)jg * 128 * 4) * 512 + lane * 8;

  // prologue: stage A tile 0 into buffer 0
#pragma unroll
  for (int cc = 0; cc < 4; ++cc) async_load16(gA[cc], &As[0][lA[cc]]);

  for (int it = 0; it < K2 / BK; ++it) {
    const int k0 = it * BK;
    const int p  = it & 1;
    __syncthreads();   // drains A prefetch (issued one iter ago) -> As[p] ready
    if (it + 1 < K2 / BK) {
#pragma unroll
      for (int cc = 0; cc < 4; ++cc)
        async_load16(gA[cc] + k0 + BK, &As[p ^ 1][lA[cc]]);
    }

    const int kt0 = k0 >> 4;
#pragma unroll
    for (int ks = 0; ks < 4; ++ks) {
      // B fragments: 4 coalesced register loads (no LDS, no barrier dep)
      bf16x8 bfr[4];
#pragma unroll
      for (int g = 0; g < 4; ++g)
        bfr[g] = *(const bf16x8*)(bbase + ((size_t)(kt0 + ks) * 4 + g) * 512);

      bf16x8 af[2];
      const int sw = ((ks * 2 + h8) ^ (l31 & 7)) * 8;
#pragma unroll
      for (int t = 0; t < 2; ++t)
        af[t] = *(const bf16x8*)&As[p][(wm * 64 + t * 32 + l31) * BK + sw];

#pragma unroll
      for (int tm = 0; tm < 2; ++tm)
#pragma unroll
        for (int g = 0; g < 4; ++g)
          acc[tm][g] = __builtin_amdgcn_mfma_f32_32x32x16_bf16(
              af[tm], bfr[g], acc[tm][g], 0, 0, 0);
    }
  }

  // epilogue: lane-local gates (gate == second acc index)
  const int j = jg * 32 + l31;
  const float vbi = bi[j], vbf = bf_[j], vbg = bg[j], vbo = bo[j];

#pragma unroll
  for (int tm = 0; tm < 2; ++tm) {
#pragma unroll
    for (int r = 0; r < 16; ++r) {
      int row = m0 + wm * 64 + tm * 32 + 4 * h8 + (r & 3) + 8 * (r >> 2);
      float gi = sigm(acc[tm][0][r] + vbi);
      float gf = sigm(acc[tm][1][r] + vbf);
      float gg = tanh_fast(acc[tm][2][r] + vbg);
      float go = sigm(acc[tm][3][r] + vbo);
      size_t idx = (size_t)row * H_DIM + j;
      float cv = c[idx];
      float nc = gf * cv + gi * gg;
      float nh = go * tanh_fast(nc);
      out_c[idx] = nc;
      out_h[idx] = nh;
    }
  }
}

extern "C" void kernel_launch(void* const* d_in, const int* in_sizes, int n_in,
                              void* d_out, int out_size, void* d_ws, size_t ws_size,
                              hipStream_t stream) {
  const float* x   = (const float*)d_in[0];
  const float* c   = (const float*)d_in[1];
  const float* h   = (const float*)d_in[2];
  const float* Wii = (const float*)d_in[3];
  const float* Wif = (const float*)d_in[4];
  const float* Wig = (const float*)d_in[5];
  const float* Wio = (const float*)d_in[6];
  const float* Whi = (const float*)d_in[7];
  const float* Whf = (const float*)d_in[8];
  const float* Whg = (const float*)d_in[9];
  const float* Who = (const float*)d_in[10];
  const float* bi  = (const float*)d_in[11];
  const float* bf_ = (const float*)d_in[12];
  const float* bg  = (const float*)d_in[13];
  const float* bo  = (const float*)d_in[14];

  __bf16* Abf = (__bf16*)d_ws;                                   // 32 MiB
  __bf16* Bt2 = (__bf16*)((char*)d_ws + (size_t)B_DIM * K2 * 2); // 16 MiB

  float* out_c = (float*)d_out;
  float* out_h = out_c + (size_t)B_DIM * H_DIM;

  cast_a<<<B_DIM, 256, 0, stream>>>(x, h, Abf);
  dim3 gw(K2 / 64, H_DIM / 32, 4);
  cast_w<<<gw, 256, 0, stream>>>(Wii, Wif, Wig, Wio, Whi, Whf, Whg, Who, Bt2);
  dim3 gg(B_DIM / BM, N4 / BN);
  lstm_gemm<<<gg, 256, 0, stream>>>(Abf, Bt2, c, bi, bf_, bg, bo, out_c, out_h);
}